// Round 19
// baseline (379.896 us; speedup 1.0000x reference)
//
#include <hip/hip_runtime.h>
#include <hip/hip_fp16.h>
#include <hip/hip_cooperative_groups.h>
#include <math.h>

namespace cg = cooperative_groups;

#define H 6
#define D 128
#define K_ALL (H * D)   // 768
#define TSTEPS 24       // K_ALL / 32
#define PADK 776        // 768 + 8 halves pad
#define NPB 8           // nodes per block (1 per wave)
#define BSTRIDE 128     // fixed col-bucket capacity per node
#define BF_PL (TSTEPS * 8 * 512)   // 98304 halves per layer

typedef _Float16 f16x8 __attribute__((ext_vector_type(8)));
typedef float f32x4 __attribute__((ext_vector_type(4)));

struct MegaArgs {
    const float* W[4];
    const float* as[4];
    const float* ad[4];
    const float* b[4];
    const float* x_in;
    const int* src;
    const int* dst;
    float* wa_all;
    _Float16* waf;
    _Float16* bf;
    int* deg;
    int* col;
    float* a0;
    float* a1;
    float* bufA;
    float* bufB;
    float* dout;
    int N, E;
};

__device__ __forceinline__ float rlf(float v, int j) {
    return __int_as_float(__builtin_amdgcn_readlane(__float_as_int(v), j));
}

// per-wave aggregate (r18-proven: no cross-lane reductions, 3-pair prefetch)
__device__ __forceinline__ void aggregate_node(const float* __restrict__ x,
                                               const float* __restrict__ a,
                                               const int* __restrict__ deg_,
                                               const int* __restrict__ col,
                                               int n, int lane,
                                               _Float16* __restrict__ xsrow) {
    const int deg = deg_[n];
    const int start = n << 7;   // BSTRIDE = 128
    const int nent = deg + 1;

    if (nent <= 64) {
        int s = n;                          // lane 'deg' = self loop
        if (lane < deg) s = col[start + lane];

        const float* xb = x + (lane << 1);
        float2 cur0, cur1, nxt0, nxt1;
        {
            int t0 = __builtin_amdgcn_readlane(s, 0);
            cur0 = *(const float2*)(xb + (size_t)t0 * D);
        }
        cur1 = make_float2(0.f, 0.f);
        nxt0 = make_float2(0.f, 0.f);
        nxt1 = make_float2(0.f, 0.f);
        if (nent > 1) {
            int t1 = __builtin_amdgcn_readlane(s, 1);
            cur1 = *(const float2*)(xb + (size_t)t1 * D);
        }
        if (nent > 2) {
            int t2 = __builtin_amdgcn_readlane(s, 2);
            nxt0 = *(const float2*)(xb + (size_t)t2 * D);
        }
        if (nent > 3) {
            int t3 = __builtin_amdgcn_readlane(s, 3);
            nxt1 = *(const float2*)(xb + (size_t)t3 * D);
        }

        float adst[H];
        #pragma unroll
        for (int h = 0; h < H; h++) adst[h] = a[(size_t)n * 12 + 6 + h];
        const float* as_ = a + (size_t)s * 12;
        float4 v0 = *(const float4*)as_;
        float2 v1 = *(const float2*)(as_ + 4);
        float e0 = v0.x + adst[0], e1 = v0.y + adst[1], e2 = v0.z + adst[2];
        float e3 = v0.w + adst[3], e4 = v1.x + adst[4], e5 = v1.y + adst[5];
        e0 = e0 > 0.f ? e0 : 0.2f * e0;  e1 = e1 > 0.f ? e1 : 0.2f * e1;
        e2 = e2 > 0.f ? e2 : 0.2f * e2;  e3 = e3 > 0.f ? e3 : 0.2f * e3;
        e4 = e4 > 0.f ? e4 : 0.2f * e4;  e5 = e5 > 0.f ? e5 : 0.2f * e5;
        float w0 = __expf(e0), w1 = __expf(e1), w2 = __expf(e2);
        float w3 = __expf(e3), w4 = __expf(e4), w5 = __expf(e5);

        float d0 = 0, d1 = 0, d2 = 0, d3 = 0, d4 = 0, d5 = 0;
        float a00 = 0, a01 = 0, a02 = 0, a03 = 0, a04 = 0, a05 = 0;
        float a10 = 0, a11 = 0, a12 = 0, a13 = 0, a14 = 0, a15 = 0;

        for (int j = 0; j < nent; j += 2) {
            float2 fut0 = make_float2(0.f, 0.f), fut1 = make_float2(0.f, 0.f);
            if (j + 4 < nent) {
                int t = __builtin_amdgcn_readlane(s, j + 4);
                fut0 = *(const float2*)(xb + (size_t)t * D);
            }
            if (j + 5 < nent) {
                int t = __builtin_amdgcn_readlane(s, j + 5);
                fut1 = *(const float2*)(xb + (size_t)t * D);
            }
            {
                float b0 = rlf(w0, j), b1 = rlf(w1, j), b2 = rlf(w2, j);
                float b3 = rlf(w3, j), b4 = rlf(w4, j), b5 = rlf(w5, j);
                d0 += b0; d1 += b1; d2 += b2; d3 += b3; d4 += b4; d5 += b5;
                a00 += b0 * cur0.x; a10 += b0 * cur0.y;
                a01 += b1 * cur0.x; a11 += b1 * cur0.y;
                a02 += b2 * cur0.x; a12 += b2 * cur0.y;
                a03 += b3 * cur0.x; a13 += b3 * cur0.y;
                a04 += b4 * cur0.x; a14 += b4 * cur0.y;
                a05 += b5 * cur0.x; a15 += b5 * cur0.y;
            }
            if (j + 1 < nent) {
                float b0 = rlf(w0, j + 1), b1 = rlf(w1, j + 1), b2 = rlf(w2, j + 1);
                float b3 = rlf(w3, j + 1), b4 = rlf(w4, j + 1), b5 = rlf(w5, j + 1);
                d0 += b0; d1 += b1; d2 += b2; d3 += b3; d4 += b4; d5 += b5;
                a00 += b0 * cur1.x; a10 += b0 * cur1.y;
                a01 += b1 * cur1.x; a11 += b1 * cur1.y;
                a02 += b2 * cur1.x; a12 += b2 * cur1.y;
                a03 += b3 * cur1.x; a13 += b3 * cur1.y;
                a04 += b4 * cur1.x; a14 += b4 * cur1.y;
                a05 += b5 * cur1.x; a15 += b5 * cur1.y;
            }
            cur0 = nxt0; cur1 = nxt1;
            nxt0 = fut0; nxt1 = fut1;
        }
        float i0 = 1.f / d0, i1 = 1.f / d1, i2 = 1.f / d2;
        float i3 = 1.f / d3, i4 = 1.f / d4, i5 = 1.f / d5;
        int c = lane << 1;
        xsrow[0 * D + c] = (_Float16)(a00 * i0);  xsrow[0 * D + c + 1] = (_Float16)(a10 * i0);
        xsrow[1 * D + c] = (_Float16)(a01 * i1);  xsrow[1 * D + c + 1] = (_Float16)(a11 * i1);
        xsrow[2 * D + c] = (_Float16)(a02 * i2);  xsrow[2 * D + c + 1] = (_Float16)(a12 * i2);
        xsrow[3 * D + c] = (_Float16)(a03 * i3);  xsrow[3 * D + c + 1] = (_Float16)(a13 * i3);
        xsrow[4 * D + c] = (_Float16)(a04 * i4);  xsrow[4 * D + c + 1] = (_Float16)(a14 * i4);
        xsrow[5 * D + c] = (_Float16)(a05 * i5);  xsrow[5 * D + c + 1] = (_Float16)(a15 * i5);
    } else {
        float adst[H];
        #pragma unroll
        for (int h = 0; h < H; h++) adst[h] = a[(size_t)n * 12 + 6 + h];
        int dl = deg < BSTRIDE ? deg : BSTRIDE;
        float d[H] = {0, 0, 0, 0, 0, 0};
        float acc0[H] = {0, 0, 0, 0, 0, 0};
        float acc1[H] = {0, 0, 0, 0, 0, 0};
        int c0 = lane, c1 = 64 + lane;
        for (int j = 0; j <= dl; j++) {
            int s = (j < dl) ? col[start + j] : n;
            float w[H];
            #pragma unroll
            for (int h = 0; h < H; h++) {
                float e = a[(size_t)s * 12 + h] + adst[h];
                e = (e > 0.f) ? e : 0.2f * e;
                w[h] = __expf(e);
                d[h] += w[h];
            }
            float xv0 = x[(size_t)s * D + c0];
            float xv1 = x[(size_t)s * D + c1];
            #pragma unroll
            for (int h = 0; h < H; h++) {
                acc0[h] += w[h] * xv0;
                acc1[h] += w[h] * xv1;
            }
        }
        #pragma unroll
        for (int h = 0; h < H; h++) {
            float inv = 1.0f / d[h];
            xsrow[h * D + c0] = (_Float16)(acc0[h] * inv);
            xsrow[h * D + c1] = (_Float16)(acc1[h] * inv);
        }
    }
}

// ---------------- the whole network in ONE cooperative kernel ----------------
__global__ __launch_bounds__(512) void mega_kernel(MegaArgs A) {
    cg::grid_group grid = cg::this_grid();
    __shared__ _Float16 xs16[16][PADK];
    __shared__ _Float16 xso[16][136];

    const int tid = (int)threadIdx.x;
    const int bid = (int)blockIdx.x;
    const int gsize = (int)gridDim.x;
    const long gtid = (long)bid * 512 + tid;
    const long gthreads = (long)gsize * 512;
    const int wave = tid >> 6;
    const int lane = tid & 63;
    const int N = A.N, E = A.E;

    // ---- phase A: zero deg + wa_all dots ----
    for (long i = gtid; i < N; i += gthreads) A.deg[i] = 0;
    for (long t = gtid; t < 4 * 1536; t += gthreads) {
        int l = (int)(t / 1536);
        int r = (int)(t % 1536);
        int k = r / 12, j = r % 12;
        int h = (j < 6) ? j : (j - 6);
        const float* att = (j < 6) ? A.as[l] : A.ad[l];
        const float* wrow = A.W[l] + (size_t)k * K_ALL + h * D;
        const float* arow = att + h * D;
        float s = 0.f;
        #pragma unroll 8
        for (int c = 0; c < D; c++) s += wrow[c] * arow[c];
        A.wa_all[(size_t)l * 1536 + k * 12 + j] = s;
    }
    grid.sync();

    // ---- phase B: scatter-hist | bf pack | waf pack | a0 via MFMA ----
    for (long e = gtid; e < E; e += gthreads) {
        int n = A.dst[e];
        int p = atomicAdd(&A.deg[n], 1);
        if (p < BSTRIDE) A.col[(size_t)n * BSTRIDE + p] = A.src[e];
    }
    for (long idx = gtid; idx < 4L * TSTEPS * 8 * 64; idx += gthreads) {
        int l63 = (int)(idx & 63);
        int ct = (int)((idx >> 6) & 7);
        int t = (int)((idx >> 9) % TSTEPS);
        int layer = (int)(idx / (TSTEPS * 8 * 64));
        const float* W = A.W[layer];
        int c = ct * 16 + (l63 & 15);
        f16x8 v;
        #pragma unroll
        for (int j = 0; j < 8; j++) {
            int k = t * 32 + ((l63 >> 4) << 3) + j;
            v[j] = (_Float16)W[(size_t)(k & 127) * K_ALL + ((k >> 7) << 7) + c];
        }
        *(f16x8*)(A.bf + (idx << 3)) = v;
    }
    for (long idx = gtid; idx < 4 * 4 * 64; idx += gthreads) {
        int L = (int)(idx >> 8);
        int t = (int)((idx >> 6) & 3);
        int ln = (int)(idx & 63);
        int j = ln & 15;
        const float* wl = A.wa_all + (size_t)L * 1536;
        f16x8 vv;
        #pragma unroll
        for (int jj = 0; jj < 8; jj++) {
            int k = t * 32 + ((ln >> 4) << 3) + jj;
            float sv = (j < 12) ? wl[k * 12 + j] : 0.f;
            vv[jj] = (_Float16)sv;
        }
        *(f16x8*)(A.waf + (size_t)L * 2048 + (size_t)t * 512 + (size_t)ln * 8) = vv;
    }
    // a0 via MFMA (reads wa_all from phase A — ordered by grid.sync)
    {
        int G0 = (N + 15) >> 4;
        for (int g = bid; g < G0; g += gsize) {
            int base_node = g << 4;
            if (tid < 256) {
                int row = tid >> 4;
                int coff = (tid & 15) * 8;
                int node = base_node + row;
                f16x8 v = {};
                if (node < N) {
                    const float* sp = A.x_in + (size_t)node * D + coff;
                    float4 u0 = *(const float4*)sp;
                    float4 u1 = *(const float4*)(sp + 4);
                    v[0] = (_Float16)u0.x; v[1] = (_Float16)u0.y;
                    v[2] = (_Float16)u0.z; v[3] = (_Float16)u0.w;
                    v[4] = (_Float16)u1.x; v[5] = (_Float16)u1.y;
                    v[6] = (_Float16)u1.z; v[7] = (_Float16)u1.w;
                }
                *(f16x8*)&xso[row][coff] = v;
            }
            __syncthreads();
            if (tid < 64) {
                int cl = tid & 15;
                int r0 = (tid >> 4) << 2;
                const float* wl0 = A.wa_all;
                f32x4 ac = {0.f, 0.f, 0.f, 0.f};
                #pragma unroll
                for (int t = 0; t < 4; t++) {
                    f16x8 av = *(const f16x8*)&xso[cl][t * 32 + ((tid >> 4) << 3)];
                    f16x8 bv;
                    #pragma unroll
                    for (int jj = 0; jj < 8; jj++) {
                        int k = t * 32 + ((tid >> 4) << 3) + jj;
                        float sv = (cl < 12) ? wl0[k * 12 + cl] : 0.f;
                        bv[jj] = (_Float16)sv;
                    }
                    ac = __builtin_amdgcn_mfma_f32_16x16x32_f16(av, bv, ac, 0, 0, 0);
                }
                if (cl < 12) {
                    #pragma unroll
                    for (int reg = 0; reg < 4; reg++) {
                        int node = base_node + r0 + reg;
                        if (node < N) A.a0[(size_t)node * 12 + cl] = ac[reg];
                    }
                }
            }
            __syncthreads();   // xso reused next group iteration
        }
    }
    grid.sync();

    // ---- 4 layers, grid.sync between ----
    const float* xcur = A.x_in;
    float* acur = A.a0;
    float* anext = A.a1;
    const int G = (N + NPB - 1) / NPB;
    for (int l = 0; l < 4; l++) {
        const _Float16* bf_l = A.bf + (size_t)l * BF_PL;
        const float* bias = A.b[l];
        float* xout = (l == 3) ? A.dout : ((l & 1) ? A.bufB : A.bufA);
        const _Float16* awf = (l < 3) ? (A.waf + (size_t)(l + 1) * 2048) : (const _Float16*)nullptr;

        for (int g = bid; g < G; g += gsize) {
            const int m0 = g << 3;
            {
                int n = m0 + wave;
                if (n < N)
                    aggregate_node(xcur, acur, A.deg, A.col, n, lane, &xs16[wave][0]);
            }
            __syncthreads();

            f32x4 acc = {0.f, 0.f, 0.f, 0.f};
            const _Float16* ars = &xs16[lane & 15][(lane >> 4) << 3];
            const _Float16* bp = bf_l + (size_t)wave * 512 + (size_t)lane * 8;
            for (int t = 0; t < TSTEPS; t++) {
                f16x8 av = *(const f16x8*)(ars + t * 32);
                f16x8 bv = *(const f16x8*)(bp + (size_t)t * 4096);
                acc = __builtin_amdgcn_mfma_f32_16x16x32_f16(av, bv, acc, 0, 0, 0);
            }

            const float inv6 = 1.0f / 6.0f;
            const int cl = lane & 15;
            const int ccol = wave * 16 + cl;
            const int r0 = (lane >> 4) << 2;
            const float bs = bias[ccol];
            #pragma unroll
            for (int reg = 0; reg < 4; reg++) {
                int ml = r0 + reg;
                int m = m0 + ml;
                float v = acc[reg] * inv6 + bs;
                v = v > 0.f ? v : 0.f;
                if (ml < NPB && m < N) xout[(size_t)m * D + ccol] = v;
                xso[ml][ccol] = (_Float16)v;
            }

            if (awf) {
                __syncthreads();
                if (wave == 0) {
                    f32x4 ac = {0.f, 0.f, 0.f, 0.f};
                    #pragma unroll
                    for (int t = 0; t < 4; t++) {
                        f16x8 av = *(const f16x8*)&xso[cl][t * 32 + ((lane >> 4) << 3)];
                        f16x8 bv = *(const f16x8*)(awf + (size_t)t * 512 + (size_t)lane * 8);
                        ac = __builtin_amdgcn_mfma_f32_16x16x32_f16(av, bv, ac, 0, 0, 0);
                    }
                    if (cl < 12) {
                        #pragma unroll
                        for (int reg = 0; reg < 4; reg++) {
                            int ml = r0 + reg;
                            int m = m0 + ml;
                            if (ml < NPB && m < N) anext[(size_t)m * 12 + cl] = ac[reg];
                        }
                    }
                }
            }
            __syncthreads();   // protect xs16/xso across group iterations
        }

        if (l < 3) grid.sync();
        xcur = xout;
        float* tmp = acur; acur = anext; anext = tmp;
    }
}

// ---------------- host ----------------

extern "C" void kernel_launch(void* const* d_in, const int* in_sizes, int n_in,
                              void* d_out, int out_size, void* d_ws, size_t ws_size,
                              hipStream_t stream) {
    const float* x_in = (const float*)d_in[0];
    const int* ei = (const int*)d_in[1];
    int N = in_sizes[0] / D;
    int E = in_sizes[1] / 2;

    float* ws = (float*)d_ws;
    float* bufA = ws;
    float* bufB = bufA + (size_t)N * D;
    float* abuf0 = bufB + (size_t)N * D;
    float* abuf1 = abuf0 + (size_t)N * 12;
    float* wa_all = abuf1 + (size_t)N * 12;          // 4*1536 floats
    _Float16* waf = (_Float16*)(wa_all + 4 * 1536);  // 4 layers x 2048 halves
    _Float16* w16f = waf + 4 * 2048;
    int* deg = (int*)(w16f + 4 * (size_t)BF_PL);
    int* col = deg + N;                               // N * BSTRIDE ints

    MegaArgs A;
    for (int l = 0; l < 4; l++) {
        A.W[l]  = (const float*)d_in[2 + 4 * l];
        A.as[l] = (const float*)d_in[3 + 4 * l];
        A.ad[l] = (const float*)d_in[4 + 4 * l];
        A.b[l]  = (const float*)d_in[5 + 4 * l];
    }
    A.x_in = x_in;
    A.src = ei;
    A.dst = ei + E;
    A.wa_all = wa_all;
    A.waf = waf;
    A.bf = w16f;
    A.deg = deg;
    A.col = col;
    A.a0 = abuf0;
    A.a1 = abuf1;
    A.bufA = bufA;
    A.bufB = bufB;
    A.dout = (float*)d_out;
    A.N = N;
    A.E = E;

    int nb = 0;
    hipOccupancyMaxActiveBlocksPerMultiprocessor(&nb, mega_kernel, 512, 0);
    if (nb < 1) nb = 1;
    int dev = 0;
    hipGetDevice(&dev);
    int numCU = 256;
    hipDeviceGetAttribute(&numCU, hipDeviceAttributeMultiprocessorCount, dev);
    int G = (N + NPB - 1) / NPB;
    int grid = nb * numCU;
    if (grid > G) grid = G;

    void* kp[] = { &A };
    hipLaunchCooperativeKernel((void*)mega_kernel, dim3(grid), dim3(512), kp, 0, stream);
}

// Round 20
// 131.562 us; speedup vs baseline: 2.8876x; 2.8876x over previous
//
#include <hip/hip_runtime.h>
#include <hip/hip_fp16.h>
#include <math.h>

#define H 6
#define D 128
#define K_ALL (H * D)   // 768
#define TSTEPS 24       // K_ALL / 32
#define PADK 776        // 768 + 8 halves pad -> conflict-free fragment reads
#define NPB 8           // nodes per block (1 per wave)
#define BSTRIDE 128     // fixed col-bucket capacity per node

typedef _Float16 f16x8 __attribute__((ext_vector_type(8)));
typedef float f32x4 __attribute__((ext_vector_type(4)));

struct FoldArgs {
    const float* W[4];
    const float* as[4];
    const float* ad[4];
};

// ---------------- K1: zero deg + wa_all dots ----------------

__global__ __launch_bounds__(256) void zero_wa_kernel(int4* __restrict__ degz, int n4,
                                                      int zBlocks, FoldArgs fa,
                                                      float* __restrict__ wa_all) {
    int b = blockIdx.x;
    int tid = threadIdx.x;
    if (b < zBlocks) {
        int i = b * 256 + tid;
        if (i < n4) degz[i] = make_int4(0, 0, 0, 0);
        return;
    }
    int t = (b - zBlocks) * 256 + tid;   // < 6144
    if (t >= 4 * 1536) return;
    int l = t / 1536;
    int r = t % 1536;
    int k = r / 12, j = r % 12;
    int h = (j < 6) ? j : (j - 6);
    const float* att = (j < 6) ? fa.as[l] : fa.ad[l];
    const float* wrow = fa.W[l] + (size_t)k * K_ALL + h * D;
    const float* arow = att + h * D;
    float s = 0.f;
    #pragma unroll 8
    for (int c = 0; c < D; c++) s += wrow[c] * arow[c];
    wa_all[(size_t)l * 1536 + k * 12 + j] = s;
}

// ---------------- K2: scatter-hist | bf pack | waf pack | layer-0 a ----------------
// a0-MFMA blocks build their L0 B-fragments inline from wa_all (K1 -> safe);
// they must NOT read waf (packed by other blocks of THIS dispatch — r16 race).

__global__ __launch_bounds__(256) void prep2_kernel(const int* __restrict__ src,
                                                    const int* __restrict__ dst,
                                                    int* __restrict__ deg,
                                                    int* __restrict__ col, int E,
                                                    int scatBlocks, FoldArgs fa,
                                                    const float* __restrict__ wa_all,
                                                    _Float16* __restrict__ waf,
                                                    _Float16* __restrict__ bf,
                                                    const float* __restrict__ x_in,
                                                    float* __restrict__ a0, int N) {
    __shared__ _Float16 xs[16][136];
    int b = blockIdx.x;
    int tid = threadIdx.x;
    if (b < scatBlocks) {
        int e = b * 256 + tid;
        if (e < E) {
            int n = dst[e];
            int p = atomicAdd(&deg[n], 1);
            if (p < BSTRIDE) col[(size_t)n * BSTRIDE + p] = src[e];
        }
        return;
    }
    int bb = b - scatBlocks;
    if (bb < 192) {
        int idx = bb * 256 + tid;    // < 49152
        int l63 = idx & 63;
        int ct = (idx >> 6) & 7;
        int t = (idx >> 9) % TSTEPS;
        int layer = idx / (TSTEPS * 8 * 64);
        const float* W = fa.W[layer];
        int c = ct * 16 + (l63 & 15);
        f16x8 v;
        #pragma unroll
        for (int j = 0; j < 8; j++) {
            int k = t * 32 + ((l63 >> 4) << 3) + j;
            v[j] = (_Float16)W[(size_t)(k & 127) * K_ALL + ((k >> 7) << 7) + c];
        }
        *(f16x8*)(bf + ((size_t)idx << 3)) = v;
        return;
    }
    bb -= 192;
    if (bb < 4) {
        int L = bb;
        int lane = tid & 63;
        int t = tid >> 6;
        int j = lane & 15;
        const float* wl = wa_all + (size_t)L * 1536;
        f16x8 vv;
        #pragma unroll
        for (int jj = 0; jj < 8; jj++) {
            int k = t * 32 + ((lane >> 4) << 3) + jj;
            float sv = (j < 12) ? wl[k * 12 + j] : 0.f;
            vv[jj] = (_Float16)sv;
        }
        *(f16x8*)(waf + (size_t)L * 2048 + (size_t)t * 512 + (size_t)lane * 8) = vv;
        return;
    }
    bb -= 4;
    // layer-0 a via MFMA: 16 nodes per block
    int base_node = bb << 4;
    {
        int row = tid >> 4;
        int coff = (tid & 15) * 8;
        int node = base_node + row;
        f16x8 v = {};
        if (node < N) {
            const float* sp = x_in + (size_t)node * D + coff;
            float4 u0 = *(const float4*)sp;
            float4 u1 = *(const float4*)(sp + 4);
            v[0] = (_Float16)u0.x; v[1] = (_Float16)u0.y;
            v[2] = (_Float16)u0.z; v[3] = (_Float16)u0.w;
            v[4] = (_Float16)u1.x; v[5] = (_Float16)u1.y;
            v[6] = (_Float16)u1.z; v[7] = (_Float16)u1.w;
        }
        *(f16x8*)&xs[row][coff] = v;
    }
    __syncthreads();
    if (tid < 64) {
        int lane = tid;
        int cl = lane & 15;
        int r0 = (lane >> 4) << 2;
        const float* wl0 = wa_all;
        f32x4 ac = {0.f, 0.f, 0.f, 0.f};
        #pragma unroll
        for (int t = 0; t < 4; t++) {
            f16x8 av = *(const f16x8*)&xs[cl][t * 32 + ((lane >> 4) << 3)];
            f16x8 bv;
            #pragma unroll
            for (int jj = 0; jj < 8; jj++) {
                int k = t * 32 + ((lane >> 4) << 3) + jj;
                float sv = (cl < 12) ? wl0[k * 12 + cl] : 0.f;
                bv[jj] = (_Float16)sv;
            }
            ac = __builtin_amdgcn_mfma_f32_16x16x32_f16(av, bv, ac, 0, 0, 0);
        }
        if (cl < 12) {
            #pragma unroll
            for (int reg = 0; reg < 4; reg++) {
                int node = base_node + r0 + reg;
                if (node < N) a0[(size_t)node * 12 + cl] = ac[reg];
            }
        }
    }
}

__device__ __forceinline__ float rlf(float v, int j) {
    return __int_as_float(__builtin_amdgcn_readlane(__float_as_int(v), j));
}

// per-wave aggregate: r14 (no cross-lane reductions) + r18 (3-pair prefetch)
// + r20: col read is UNCONDITIONAL so the deg and col loads issue in
// parallel (one L2 round trip saved per node head). Garbage col values for
// lanes >= deg are range-clamped so the speculative x-prefetch stays
// in-bounds; those lanes are never broadcast (j < nent).
__device__ __forceinline__ void aggregate_node(const float* __restrict__ x,
                                               const float* __restrict__ a,
                                               const int* __restrict__ deg_,
                                               const int* __restrict__ col,
                                               int n, int lane, int Nn,
                                               _Float16* __restrict__ xsrow) {
    const int deg = deg_[n];
    const int start = n << 7;   // BSTRIDE = 128
    int colv = col[start + lane];          // independent of deg load
    const int nent = deg + 1;

    if (nent <= 64) {
        int sc = ((unsigned)colv < (unsigned)Nn) ? colv : n;  // sanitize garbage
        int s = (lane < deg) ? sc : n;      // lane 'deg' = self loop

        // ---- x prefetch head: depends only on s ----
        const float* xb = x + (lane << 1);
        float2 cur0, cur1, nxt0, nxt1;
        {
            int t0 = __builtin_amdgcn_readlane(s, 0);
            cur0 = *(const float2*)(xb + (size_t)t0 * D);
        }
        cur1 = make_float2(0.f, 0.f);
        nxt0 = make_float2(0.f, 0.f);
        nxt1 = make_float2(0.f, 0.f);
        if (nent > 1) {
            int t1 = __builtin_amdgcn_readlane(s, 1);
            cur1 = *(const float2*)(xb + (size_t)t1 * D);
        }
        if (nent > 2) {
            int t2 = __builtin_amdgcn_readlane(s, 2);
            nxt0 = *(const float2*)(xb + (size_t)t2 * D);
        }
        if (nent > 3) {
            int t3 = __builtin_amdgcn_readlane(s, 3);
            nxt1 = *(const float2*)(xb + (size_t)t3 * D);
        }

        // ---- logits + exp (overlaps prefetch latency) ----
        float adst[H];
        #pragma unroll
        for (int h = 0; h < H; h++) adst[h] = a[(size_t)n * 12 + 6 + h];
        const float* as_ = a + (size_t)s * 12;
        float4 v0 = *(const float4*)as_;
        float2 v1 = *(const float2*)(as_ + 4);
        float e0 = v0.x + adst[0], e1 = v0.y + adst[1], e2 = v0.z + adst[2];
        float e3 = v0.w + adst[3], e4 = v1.x + adst[4], e5 = v1.y + adst[5];
        e0 = e0 > 0.f ? e0 : 0.2f * e0;  e1 = e1 > 0.f ? e1 : 0.2f * e1;
        e2 = e2 > 0.f ? e2 : 0.2f * e2;  e3 = e3 > 0.f ? e3 : 0.2f * e3;
        e4 = e4 > 0.f ? e4 : 0.2f * e4;  e5 = e5 > 0.f ? e5 : 0.2f * e5;
        float w0 = __expf(e0), w1 = __expf(e1), w2 = __expf(e2);
        float w3 = __expf(e3), w4 = __expf(e4), w5 = __expf(e5);

        float d0 = 0, d1 = 0, d2 = 0, d3 = 0, d4 = 0, d5 = 0;
        float a00 = 0, a01 = 0, a02 = 0, a03 = 0, a04 = 0, a05 = 0;
        float a10 = 0, a11 = 0, a12 = 0, a13 = 0, a14 = 0, a15 = 0;

        for (int j = 0; j < nent; j += 2) {
            float2 fut0 = make_float2(0.f, 0.f), fut1 = make_float2(0.f, 0.f);
            if (j + 4 < nent) {
                int t = __builtin_amdgcn_readlane(s, j + 4);
                fut0 = *(const float2*)(xb + (size_t)t * D);
            }
            if (j + 5 < nent) {
                int t = __builtin_amdgcn_readlane(s, j + 5);
                fut1 = *(const float2*)(xb + (size_t)t * D);
            }
            {
                float b0 = rlf(w0, j), b1 = rlf(w1, j), b2 = rlf(w2, j);
                float b3 = rlf(w3, j), b4 = rlf(w4, j), b5 = rlf(w5, j);
                d0 += b0; d1 += b1; d2 += b2; d3 += b3; d4 += b4; d5 += b5;
                a00 += b0 * cur0.x; a10 += b0 * cur0.y;
                a01 += b1 * cur0.x; a11 += b1 * cur0.y;
                a02 += b2 * cur0.x; a12 += b2 * cur0.y;
                a03 += b3 * cur0.x; a13 += b3 * cur0.y;
                a04 += b4 * cur0.x; a14 += b4 * cur0.y;
                a05 += b5 * cur0.x; a15 += b5 * cur0.y;
            }
            if (j + 1 < nent) {
                float b0 = rlf(w0, j + 1), b1 = rlf(w1, j + 1), b2 = rlf(w2, j + 1);
                float b3 = rlf(w3, j + 1), b4 = rlf(w4, j + 1), b5 = rlf(w5, j + 1);
                d0 += b0; d1 += b1; d2 += b2; d3 += b3; d4 += b4; d5 += b5;
                a00 += b0 * cur1.x; a10 += b0 * cur1.y;
                a01 += b1 * cur1.x; a11 += b1 * cur1.y;
                a02 += b2 * cur1.x; a12 += b2 * cur1.y;
                a03 += b3 * cur1.x; a13 += b3 * cur1.y;
                a04 += b4 * cur1.x; a14 += b4 * cur1.y;
                a05 += b5 * cur1.x; a15 += b5 * cur1.y;
            }
            cur0 = nxt0; cur1 = nxt1;
            nxt0 = fut0; nxt1 = fut1;
        }
        float i0 = 1.f / d0, i1 = 1.f / d1, i2 = 1.f / d2;
        float i3 = 1.f / d3, i4 = 1.f / d4, i5 = 1.f / d5;
        int c = lane << 1;
        xsrow[0 * D + c] = (_Float16)(a00 * i0);  xsrow[0 * D + c + 1] = (_Float16)(a10 * i0);
        xsrow[1 * D + c] = (_Float16)(a01 * i1);  xsrow[1 * D + c + 1] = (_Float16)(a11 * i1);
        xsrow[2 * D + c] = (_Float16)(a02 * i2);  xsrow[2 * D + c + 1] = (_Float16)(a12 * i2);
        xsrow[3 * D + c] = (_Float16)(a03 * i3);  xsrow[3 * D + c + 1] = (_Float16)(a13 * i3);
        xsrow[4 * D + c] = (_Float16)(a04 * i4);  xsrow[4 * D + c + 1] = (_Float16)(a14 * i4);
        xsrow[5 * D + c] = (_Float16)(a05 * i5);  xsrow[5 * D + c + 1] = (_Float16)(a15 * i5);
    } else {
        // slow fallback (64 <= deg): single pass, no max-subtract.
        float adst[H];
        #pragma unroll
        for (int h = 0; h < H; h++) adst[h] = a[(size_t)n * 12 + 6 + h];
        int dl = deg < BSTRIDE ? deg : BSTRIDE;
        float d[H] = {0, 0, 0, 0, 0, 0};
        float acc0[H] = {0, 0, 0, 0, 0, 0};
        float acc1[H] = {0, 0, 0, 0, 0, 0};
        int c0 = lane, c1 = 64 + lane;
        for (int j = 0; j <= dl; j++) {
            int s = (j < dl) ? col[start + j] : n;
            float w[H];
            #pragma unroll
            for (int h = 0; h < H; h++) {
                float e = a[(size_t)s * 12 + h] + adst[h];
                e = (e > 0.f) ? e : 0.2f * e;
                w[h] = __expf(e);
                d[h] += w[h];
            }
            float xv0 = x[(size_t)s * D + c0];
            float xv1 = x[(size_t)s * D + c1];
            #pragma unroll
            for (int h = 0; h < H; h++) {
                acc0[h] += w[h] * xv0;
                acc1[h] += w[h] * xv1;
            }
        }
        #pragma unroll
        for (int h = 0; h < H; h++) {
            float inv = 1.0f / d[h];
            xsrow[h * D + c0] = (_Float16)(acc0[h] * inv);
            xsrow[h * D + c1] = (_Float16)(acc1[h] * inv);
        }
    }
}

// ---------------- fused layer: aggregate(8 nodes -> LDS) + MFMA GEMM + a ----------------
__global__ __launch_bounds__(512) void layer_kernel(const float* __restrict__ x,
                                                    const float* __restrict__ a_in,
                                                    const int* __restrict__ deg_,
                                                    const int* __restrict__ col,
                                                    const _Float16* __restrict__ bf,
                                                    const float* __restrict__ bias,
                                                    float* __restrict__ xout,
                                                    const _Float16* __restrict__ awf,
                                                    float* __restrict__ a_out, int M) {
    __shared__ _Float16 xs16[16][PADK];   // rows 0..7 aggregated; 8..15 garbage
    __shared__ _Float16 xso[16][136];     // output rows (f16) for fused a
    const int wave = (int)(threadIdx.x >> 6);
    const int lane = (int)(threadIdx.x & 63);
    const int m0 = (int)(blockIdx.x << 3);

    // phase 1: each wave aggregates 1 node
    {
        int n = m0 + wave;
        if (n < M)
            aggregate_node(x, a_in, deg_, col, n, lane, M, &xs16[wave][0]);
    }
    __syncthreads();

    // phase 2: GEMM — wave w owns col-tile w (cols w*16..w*16+15)
    f32x4 acc = {0.f, 0.f, 0.f, 0.f};
    const _Float16* ars = &xs16[lane & 15][(lane >> 4) << 3];
    const _Float16* bp = bf + (size_t)wave * 512 + (size_t)lane * 8;
    for (int t = 0; t < TSTEPS; t++) {
        f16x8 av = *(const f16x8*)(ars + t * 32);
        f16x8 bv = *(const f16x8*)(bp + (size_t)t * 4096);
        acc = __builtin_amdgcn_mfma_f32_16x16x32_f16(av, bv, acc, 0, 0, 0);
    }

    const float inv6 = 1.0f / 6.0f;
    const int cl = lane & 15;
    const int ccol = wave * 16 + cl;
    const int r0 = (lane >> 4) << 2;
    const float bs = bias[ccol];
    #pragma unroll
    for (int reg = 0; reg < 4; reg++) {
        int ml = r0 + reg;
        int m = m0 + ml;
        float v = acc[reg] * inv6 + bs;
        v = v > 0.f ? v : 0.f;
        if (ml < NPB && m < M) xout[(size_t)m * D + ccol] = v;
        xso[ml][ccol] = (_Float16)v;
    }

    // phase 3: fused next-layer attention logits (wave 0)
    if (awf) {
        __syncthreads();
        if (wave == 0) {
            f32x4 ac = {0.f, 0.f, 0.f, 0.f};
            #pragma unroll
            for (int t = 0; t < 4; t++) {
                f16x8 av = *(const f16x8*)&xso[cl][t * 32 + ((lane >> 4) << 3)];
                f16x8 bv = *(const f16x8*)(awf + (size_t)t * 512 + (size_t)lane * 8);
                ac = __builtin_amdgcn_mfma_f32_16x16x32_f16(av, bv, ac, 0, 0, 0);
            }
            if (cl < 12) {
                #pragma unroll
                for (int reg = 0; reg < 4; reg++) {
                    int ml = r0 + reg;
                    int m = m0 + ml;
                    if (ml < NPB && m < M) a_out[(size_t)m * 12 + cl] = ac[reg];
                }
            }
        }
    }
}

// ---------------- host ----------------

extern "C" void kernel_launch(void* const* d_in, const int* in_sizes, int n_in,
                              void* d_out, int out_size, void* d_ws, size_t ws_size,
                              hipStream_t stream) {
    const float* x_in = (const float*)d_in[0];
    const int* ei = (const int*)d_in[1];
    int N = in_sizes[0] / D;
    int E = in_sizes[1] / 2;
    const int* srcp = ei;
    const int* dstp = ei + E;

    size_t bf_halves_per_layer = (size_t)TSTEPS * 8 * 512;   // 98304

    float* ws = (float*)d_ws;
    float* bufA = ws;
    float* bufB = bufA + (size_t)N * D;
    float* abuf0 = bufB + (size_t)N * D;
    float* abuf1 = abuf0 + (size_t)N * 12;
    float* wa_all = abuf1 + (size_t)N * 12;          // 4*1536 floats
    _Float16* waf = (_Float16*)(wa_all + 4 * 1536);  // 4 layers x 2048 halves
    _Float16* w16f = waf + 4 * 2048;
    int* deg = (int*)(w16f + 4 * bf_halves_per_layer);
    int* col = deg + N;                               // N * BSTRIDE ints

    FoldArgs fa;
    for (int l = 0; l < 4; l++) {
        fa.W[l]  = (const float*)d_in[2 + 4 * l];
        fa.as[l] = (const float*)d_in[3 + 4 * l];
        fa.ad[l] = (const float*)d_in[4 + 4 * l];
    }

    // K1: zero deg + wa_all dots
    int n4 = (N + 3) / 4;
    int zBlocks = (n4 + 255) / 256;
    zero_wa_kernel<<<zBlocks + 24, 256, 0, stream>>>((int4*)deg, n4, zBlocks, fa, wa_all);

    // K2: scatter-hist | bf pack | waf pack | layer-0 a
    int scatBlocks = (E + 255) / 256;
    int a0Blocks = (N + 15) / 16;
    prep2_kernel<<<scatBlocks + 192 + 4 + a0Blocks, 256, 0, stream>>>(
        srcp, dstp, deg, col, E, scatBlocks, fa, wa_all, waf, w16f, x_in, abuf0, N);

    const float* xcur = x_in;
    float* acur = abuf0;
    float* anext = abuf1;
    for (int l = 0; l < 4; l++) {
        const float* b = (const float*)d_in[5 + 4 * l];
        float* xout = (l == 3) ? (float*)d_out : ((l & 1) ? bufB : bufA);
        const _Float16* awf = (l < 3) ? (waf + (size_t)(l + 1) * 2048) : (const _Float16*)nullptr;

        layer_kernel<<<(N + NPB - 1) / NPB, 512, 0, stream>>>(xcur, acur, deg, col,
                                                              w16f + (size_t)l * bf_halves_per_layer,
                                                              b, xout, awf, anext, N);
        xcur = xout;
        float* tmp = acur; acur = anext; anext = tmp;
    }
}